// Round 1
// baseline (557.406 us; speedup 1.0000x reference)
//
#include <hip/hip_runtime.h>
#include <hip/hip_bf16.h>

#define NN 50000
#define EE 800000
#define CIN 256
#define HEADS 4
#define HDIM 32
#define PROJ_COLS 416   // 128 q | 128 k | 128 v | 32 skip

// ---------------- SGEMM: proj = x @ [Wq|Wk|Wv|Ws] + bias ----------------
// BM=64, BN=32, BK=16, 256 threads, 4x2 micro-tile per thread.
#define BM 64
#define BN 32
#define BK 16

__global__ __launch_bounds__(256) void sgemm_qkvs(
    const float* __restrict__ x,
    const float* __restrict__ Wq, const float* __restrict__ bq,
    const float* __restrict__ Wk, const float* __restrict__ bk,
    const float* __restrict__ Wv, const float* __restrict__ bv,
    const float* __restrict__ Ws, const float* __restrict__ bs,
    float* __restrict__ proj)
{
    __shared__ float As[BM][BK + 1];   // +1 pad: ty-stride 68 -> distinct banks
    __shared__ float Bs[BK][BN];

    const int row0 = blockIdx.x * BM;
    const int col0 = blockIdx.y * BN;  // 0..415, each 32-col tile within one W

    const float* W; const float* bias; int wcols; int wcol0;
    if (col0 < 128)      { W = Wq; bias = bq; wcols = 128; wcol0 = col0;       }
    else if (col0 < 256) { W = Wk; bias = bk; wcols = 128; wcol0 = col0 - 128; }
    else if (col0 < 384) { W = Wv; bias = bv; wcols = 128; wcol0 = col0 - 256; }
    else                 { W = Ws; bias = bs; wcols = 32;  wcol0 = col0 - 384; }

    const int tid = threadIdx.x;
    const int tx = tid & 15;        // 0..15 -> 2 cols each
    const int ty = tid >> 4;        // 0..15 -> 4 rows each

    // global->LDS load indices
    const int aRow  = tid >> 2;        // 0..63
    const int aCol4 = (tid & 3) * 4;   // 0,4,8,12
    const int bRow  = tid >> 4;        // 0..15
    const int bCol2 = (tid & 15) * 2;  // 0..30

    float acc[4][2] = {};

    for (int k0 = 0; k0 < CIN; k0 += BK) {
        float4 av = make_float4(0.f, 0.f, 0.f, 0.f);
        const int gr = row0 + aRow;
        if (gr < NN) av = *(const float4*)&x[(size_t)gr * CIN + k0 + aCol4];
        As[aRow][aCol4 + 0] = av.x;
        As[aRow][aCol4 + 1] = av.y;
        As[aRow][aCol4 + 2] = av.z;
        As[aRow][aCol4 + 3] = av.w;

        float2 bv2 = *(const float2*)&W[(size_t)(k0 + bRow) * wcols + wcol0 + bCol2];
        Bs[bRow][bCol2 + 0] = bv2.x;
        Bs[bRow][bCol2 + 1] = bv2.y;
        __syncthreads();

        #pragma unroll
        for (int kk = 0; kk < BK; ++kk) {
            const float b0 = Bs[kk][tx * 2 + 0];
            const float b1 = Bs[kk][tx * 2 + 1];
            #pragma unroll
            for (int i = 0; i < 4; ++i) {
                const float a = As[ty * 4 + i][kk];
                acc[i][0] += a * b0;
                acc[i][1] += a * b1;
            }
        }
        __syncthreads();
    }

    #pragma unroll
    for (int i = 0; i < 4; ++i) {
        const int gr = row0 + ty * 4 + i;
        if (gr < NN) {
            #pragma unroll
            for (int j = 0; j < 2; ++j) {
                proj[(size_t)gr * PROJ_COLS + col0 + tx * 2 + j] =
                    acc[i][j] + bias[wcol0 + tx * 2 + j];
            }
        }
    }
}

// ---------------- Edge pass 1: logits -> exp, segment sum ----------------
// one thread per (edge, head); q at proj col 0, k at col 128
__global__ __launch_bounds__(256) void edge_logits(
    const float* __restrict__ proj, const int* __restrict__ ei,
    float* __restrict__ ew, float* __restrict__ ssum)
{
    const int t = blockIdx.x * 256 + threadIdx.x;   // e*4 + h
    if (t >= EE * HEADS) return;
    const int e = t >> 2;
    const int h = t & 3;
    const int src = ei[e];
    const int dst = ei[EE + e];

    const float* qp = proj + (size_t)dst * PROJ_COLS + h * HDIM;
    const float* kp = proj + (size_t)src * PROJ_COLS + 128 + h * HDIM;

    float sum = 0.f;
    #pragma unroll
    for (int j = 0; j < 8; ++j) {
        const float4 qv = *(const float4*)(qp + j * 4);
        const float4 kv = *(const float4*)(kp + j * 4);
        sum += qv.x * kv.x + qv.y * kv.y + qv.z * kv.z + qv.w * kv.w;
    }
    // scale = 1/sqrt(32); exp without max-shift (logits ~ N(0,1), safe in f32)
    const float ev = __expf(sum * 0.17677669529663687f);
    ew[t] = ev;
    unsafeAtomicAdd(&ssum[(size_t)dst * HEADS + h], ev);
}

// ---------------- Edge pass 2: weighted scatter of V (head-mean fused) ----
// one thread per (edge, channel c in 0..31)
__global__ __launch_bounds__(256) void edge_accum(
    const float* __restrict__ proj, const int* __restrict__ ei,
    const float* __restrict__ ew, const float* __restrict__ ssum,
    float* __restrict__ accum)
{
    const int t = blockIdx.x * 256 + threadIdx.x;   // e*32 + c
    if (t >= EE * HDIM) return;
    const int e = t >> 5;
    const int c = t & 31;
    const int src = ei[e];
    const int dst = ei[EE + e];

    const float* vp = proj + (size_t)src * PROJ_COLS + 256;
    float sum = 0.f;
    #pragma unroll
    for (int h = 0; h < HEADS; ++h) {
        const float w = ew[e * HEADS + h] / ssum[(size_t)dst * HEADS + h];
        sum += w * vp[h * HDIM + c];
    }
    unsafeAtomicAdd(&accum[(size_t)dst * HDIM + c], 0.25f * sum);
}

// ---------------- Finalize: accum + skip, LeakyReLU ----------------
__global__ __launch_bounds__(256) void finalize(
    const float* __restrict__ accum, const float* __restrict__ proj,
    float* __restrict__ out)
{
    const int t = blockIdx.x * 256 + threadIdx.x;
    if (t >= NN * HDIM) return;
    const int n = t >> 5;
    const int c = t & 31;
    const float v = accum[t] + proj[(size_t)n * PROJ_COLS + 384 + c];
    out[t] = v > 0.f ? v : 0.1f * v;
}

extern "C" void kernel_launch(void* const* d_in, const int* in_sizes, int n_in,
                              void* d_out, int out_size, void* d_ws, size_t ws_size,
                              hipStream_t stream) {
    const float* x  = (const float*)d_in[0];
    const int*   ei = (const int*)d_in[1];
    const float* Wq = (const float*)d_in[2];
    const float* bq = (const float*)d_in[3];
    const float* Wk = (const float*)d_in[4];
    const float* bk = (const float*)d_in[5];
    const float* Wv = (const float*)d_in[6];
    const float* bv = (const float*)d_in[7];
    const float* Ws = (const float*)d_in[8];
    const float* bs = (const float*)d_in[9];
    float* out = (float*)d_out;

    // ws layout (all 16B aligned)
    char* ws = (char*)d_ws;
    float* proj  = (float*)(ws);                                   // N*416*4 = 83.2 MB
    float* ew    = (float*)(ws + (size_t)NN * PROJ_COLS * 4);      // E*4*4   = 12.8 MB
    float* ssum  = (float*)(ws + (size_t)NN * PROJ_COLS * 4 + (size_t)EE * HEADS * 4); // 800 KB
    float* accum = (float*)((char*)ssum + (size_t)NN * HEADS * 4); // 6.4 MB

    hipMemsetAsync(ssum, 0, (size_t)NN * HEADS * 4, stream);
    hipMemsetAsync(accum, 0, (size_t)NN * HDIM * 4, stream);

    dim3 gGemm((NN + BM - 1) / BM, PROJ_COLS / BN);
    sgemm_qkvs<<<gGemm, 256, 0, stream>>>(x, Wq, bq, Wk, bk, Wv, bv, Ws, bs, proj);

    const int tLog = EE * HEADS;
    edge_logits<<<(tLog + 255) / 256, 256, 0, stream>>>(proj, ei, ew, ssum);

    const int tAcc = EE * HDIM;
    edge_accum<<<(tAcc + 255) / 256, 256, 0, stream>>>(proj, ei, ew, ssum, accum);

    const int tFin = NN * HDIM;
    finalize<<<(tFin + 255) / 256, 256, 0, stream>>>(accum, proj, out);
}

// Round 2
// 336.731 us; speedup vs baseline: 1.6553x; 1.6553x over previous
//
#include <hip/hip_runtime.h>
#include <hip/hip_bf16.h>

#define NN 50000
#define EE 800000
#define CIN 256
#define HEADS 4
#define HDIM 32

typedef float f32x4 __attribute__((ext_vector_type(4)));
typedef __bf16 bf16x8 __attribute__((ext_vector_type(8)));

typedef const __attribute__((address_space(1))) unsigned int* gptr_t;
typedef __attribute__((address_space(3))) unsigned int* lptr_t;

static __device__ __forceinline__ unsigned short f2b(float f) {
    __hip_bfloat16 h = __float2bfloat16(f);
    return *(unsigned short*)&h;
}
static __device__ __forceinline__ float blo(unsigned int u) {
    union { unsigned int i; float f; } c; c.i = u << 16; return c.f;
}
static __device__ __forceinline__ float bhi(unsigned int u) {
    union { unsigned int i; float f; } c; c.i = u & 0xffff0000u; return c.f;
}

// ---------------- prep: x -> bf16 ----------------
__global__ __launch_bounds__(256) void prep_x(const float* __restrict__ x,
                                              unsigned short* __restrict__ xb) {
    const int t = blockIdx.x * 256 + threadIdx.x;     // one thread per 8 elements
    if (t >= NN * CIN / 8) return;
    const float4 a = ((const float4*)x)[t * 2];
    const float4 b = ((const float4*)x)[t * 2 + 1];
    union { unsigned short us[8]; uint4 v; } o;
    o.us[0] = f2b(a.x); o.us[1] = f2b(a.y); o.us[2] = f2b(a.z); o.us[3] = f2b(a.w);
    o.us[4] = f2b(b.x); o.us[5] = f2b(b.y); o.us[6] = f2b(b.z); o.us[7] = f2b(b.w);
    ((uint4*)xb)[t] = o.v;
}

// ---------------- prep: WT[416][256] bf16 (transposed concat) ----------------
__global__ __launch_bounds__(256) void prep_w(
    const float* __restrict__ Wq, const float* __restrict__ Wk,
    const float* __restrict__ Wv, const float* __restrict__ Ws,
    unsigned short* __restrict__ WT) {
    const int t = blockIdx.x * 256 + threadIdx.x;     // c*256 + k
    if (t >= 416 * 256) return;
    const int c = t >> 8;
    const int k = t & 255;
    float w;
    if (c < 128)      w = Wq[k * 128 + c];
    else if (c < 256) w = Wk[k * 128 + (c - 128)];
    else if (c < 384) w = Wv[k * 128 + (c - 256)];
    else              w = Ws[k * 32 + (c - 384)];
    WT[t] = f2b(w);
}

// ---------------- MFMA GEMM: [N][256]bf16 @ WT -> q/k/v bf16, skip f32 ------
// block = 256 threads (4 waves), tile 128 rows x 32 cols, BK=32
__global__ __launch_bounds__(256) void mfma_gemm(
    const unsigned short* __restrict__ xb, const unsigned short* __restrict__ WT,
    const float* __restrict__ bq, const float* __restrict__ bk,
    const float* __restrict__ bv, const float* __restrict__ bs,
    unsigned short* __restrict__ qb, unsigned short* __restrict__ kb,
    unsigned short* __restrict__ vb, float* __restrict__ skip) {
    __shared__ __hip_bfloat16 As[128 * 32];   // row-major [r][k], unit u(16B): r=u>>2, kchunk=u&3
    __shared__ __hip_bfloat16 Bs[32 * 32];    // col-major [c][k], unit u: c=u>>2, kchunk=u&3

    const int row0 = blockIdx.x * 128;
    const int col0 = blockIdx.y * 32;
    const int wave = threadIdx.x >> 6;
    const int lane = threadIdx.x & 63;
    const int lr = lane & 15;
    const int lq = lane >> 4;

    f32x4 acc[2][2] = {};

    for (int k0 = 0; k0 < CIN; k0 += 32) {
        // stage A: 2 issues per wave, 16B each lane, LDS linear
        #pragma unroll
        for (int i = 0; i < 2; ++i) {
            const int u = wave * 128 + i * 64 + lane;
            const int r = u >> 2, cb = u & 3;
            int grow = row0 + r; if (grow >= NN) grow = NN - 1;
            __builtin_amdgcn_global_load_lds(
                (gptr_t)(const void*)(xb + (size_t)grow * CIN + k0 + cb * 8),
                (lptr_t)(void*)((__hip_bfloat16*)As + u * 8), 16, 0, 0);
        }
        // stage B: waves 0,1
        if (wave < 2) {
            const int u = wave * 64 + lane;
            const int c = u >> 2, cb = u & 3;
            __builtin_amdgcn_global_load_lds(
                (gptr_t)(const void*)(WT + (size_t)(col0 + c) * CIN + k0 + cb * 8),
                (lptr_t)(void*)((__hip_bfloat16*)Bs + u * 8), 16, 0, 0);
        }
        __syncthreads();

        bf16x8 af[2], bfr[2];
        af[0]  = *(const bf16x8*)(As + (wave * 32 +  0 + lr) * 32 + lq * 8);
        af[1]  = *(const bf16x8*)(As + (wave * 32 + 16 + lr) * 32 + lq * 8);
        bfr[0] = *(const bf16x8*)(Bs + ( 0 + lr) * 32 + lq * 8);
        bfr[1] = *(const bf16x8*)(Bs + (16 + lr) * 32 + lq * 8);

        acc[0][0] = __builtin_amdgcn_mfma_f32_16x16x32_bf16(af[0], bfr[0], acc[0][0], 0, 0, 0);
        acc[0][1] = __builtin_amdgcn_mfma_f32_16x16x32_bf16(af[0], bfr[1], acc[0][1], 0, 0, 0);
        acc[1][0] = __builtin_amdgcn_mfma_f32_16x16x32_bf16(af[1], bfr[0], acc[1][0], 0, 0, 0);
        acc[1][1] = __builtin_amdgcn_mfma_f32_16x16x32_bf16(af[1], bfr[1], acc[1][1], 0, 0, 0);
        __syncthreads();
    }

    // epilogue: C/D layout col=lane&15, row=(lane>>4)*4+reg [m89]
    #pragma unroll
    for (int i = 0; i < 2; ++i)
        #pragma unroll
        for (int j = 0; j < 2; ++j)
            #pragma unroll
            for (int r = 0; r < 4; ++r) {
                const int grow = row0 + wave * 32 + i * 16 + lq * 4 + r;
                if (grow >= NN) continue;
                const int gcol = col0 + j * 16 + lr;
                const float val = acc[i][j][r];
                if (gcol < 128)
                    qb[(size_t)grow * 128 + gcol] = f2b(val + bq[gcol]);
                else if (gcol < 256)
                    kb[(size_t)grow * 128 + gcol - 128] = f2b(val + bk[gcol - 128]);
                else if (gcol < 384)
                    vb[(size_t)grow * 128 + gcol - 256] = f2b(val + bv[gcol - 256]);
                else
                    skip[(size_t)grow * 32 + gcol - 384] = val + bs[gcol - 384];
            }
}

// ---------------- Edge pass 1: exp(logit), segment sum ----------------
__global__ __launch_bounds__(256) void edge_logits(
    const unsigned short* __restrict__ qb, const unsigned short* __restrict__ kb,
    const int* __restrict__ ei, float* __restrict__ ew, float* __restrict__ ssum) {
    const int t = blockIdx.x * 256 + threadIdx.x;   // e*4 + h
    if (t >= EE * HEADS) return;
    const int e = t >> 2;
    const int h = t & 3;
    const int src = ei[e];
    const int dst = ei[EE + e];

    const uint4* qp = (const uint4*)(qb + (size_t)dst * 128 + h * 32);
    const uint4* kp = (const uint4*)(kb + (size_t)src * 128 + h * 32);

    float dot = 0.f;
    #pragma unroll
    for (int j = 0; j < 4; ++j) {
        const uint4 qv = qp[j];
        const uint4 kv = kp[j];
        dot += blo(qv.x) * blo(kv.x) + bhi(qv.x) * bhi(kv.x);
        dot += blo(qv.y) * blo(kv.y) + bhi(qv.y) * bhi(kv.y);
        dot += blo(qv.z) * blo(kv.z) + bhi(qv.z) * bhi(kv.z);
        dot += blo(qv.w) * blo(kv.w) + bhi(qv.w) * bhi(kv.w);
    }
    // exp without max-shift: logits ~N(0,1), max over 3.2M ~5.5 -> safe in f32
    const float ev = __expf(dot * 0.17677669529663687f);
    ew[t] = ev;
    unsafeAtomicAdd(&ssum[(size_t)dst * HEADS + h], ev);
}

// ---------------- alpha = 0.25 * e / ssum[dst] ----------------
__global__ __launch_bounds__(256) void edge_alpha(
    const int* __restrict__ ei, float* __restrict__ ew,
    const float* __restrict__ ssum) {
    const int t = blockIdx.x * 256 + threadIdx.x;   // e*4 + h
    if (t >= EE * HEADS) return;
    const int e = t >> 2;
    const int h = t & 3;
    const int dst = ei[EE + e];
    ew[t] = 0.25f * ew[t] / ssum[(size_t)dst * HEADS + h];
}

// ---------------- Edge pass 2: weighted scatter of V ----------------
__global__ __launch_bounds__(256) void edge_accum(
    const unsigned short* __restrict__ vb, const int* __restrict__ ei,
    const float* __restrict__ ew, float* __restrict__ accum) {
    const int t = blockIdx.x * 256 + threadIdx.x;   // e*32 + c
    if (t >= EE * HDIM) return;
    const int e = t >> 5;
    const int c = t & 31;
    const int src = ei[e];
    const int dst = ei[EE + e];

    float sum = 0.f;
    #pragma unroll
    for (int h = 0; h < HEADS; ++h) {
        const float a = ew[e * HEADS + h];
        union { unsigned int i; float f; } cv;
        cv.i = ((unsigned int)vb[(size_t)src * 128 + h * 32 + c]) << 16;
        sum += a * cv.f;
    }
    unsafeAtomicAdd(&accum[(size_t)dst * HDIM + c], sum);
}

// ---------------- Finalize ----------------
__global__ __launch_bounds__(256) void finalize(
    const float* __restrict__ accum, const float* __restrict__ skip,
    float* __restrict__ out) {
    const int t = blockIdx.x * 256 + threadIdx.x;
    if (t >= NN * HDIM) return;
    const float v = accum[t] + skip[t];
    out[t] = v > 0.f ? v : 0.1f * v;
}

extern "C" void kernel_launch(void* const* d_in, const int* in_sizes, int n_in,
                              void* d_out, int out_size, void* d_ws, size_t ws_size,
                              hipStream_t stream) {
    const float* x  = (const float*)d_in[0];
    const int*   ei = (const int*)d_in[1];
    const float* Wq = (const float*)d_in[2];
    const float* bq = (const float*)d_in[3];
    const float* Wk = (const float*)d_in[4];
    const float* bk = (const float*)d_in[5];
    const float* Wv = (const float*)d_in[6];
    const float* bv = (const float*)d_in[7];
    const float* Ws = (const float*)d_in[8];
    const float* bs = (const float*)d_in[9];
    float* out = (float*)d_out;

    // ws layout (256B-aligned offsets)
    char* ws = (char*)d_ws;
    size_t off = 0;
    unsigned short* xb = (unsigned short*)(ws + off); off += (size_t)NN * CIN * 2;       // 25.6 MB
    off = (off + 255) & ~(size_t)255;
    unsigned short* WT = (unsigned short*)(ws + off); off += (size_t)416 * CIN * 2;      // 213 KB
    off = (off + 255) & ~(size_t)255;
    unsigned short* qb = (unsigned short*)(ws + off); off += (size_t)NN * 128 * 2;       // 12.8 MB
    off = (off + 255) & ~(size_t)255;
    unsigned short* kb = (unsigned short*)(ws + off); off += (size_t)NN * 128 * 2;
    off = (off + 255) & ~(size_t)255;
    unsigned short* vb = (unsigned short*)(ws + off); off += (size_t)NN * 128 * 2;
    off = (off + 255) & ~(size_t)255;
    float* skip = (float*)(ws + off); off += (size_t)NN * HDIM * 4;                      // 6.4 MB
    off = (off + 255) & ~(size_t)255;
    float* ew = (float*)(ws + off); off += (size_t)EE * HEADS * 4;                       // 12.8 MB
    off = (off + 255) & ~(size_t)255;
    float* ssum = (float*)(ws + off); off += (size_t)NN * HEADS * 4;                     // 800 KB
    off = (off + 255) & ~(size_t)255;
    float* accum = (float*)(ws + off); off += (size_t)NN * HDIM * 4;                     // 6.4 MB

    hipMemsetAsync(ssum, 0, (size_t)NN * HEADS * 4, stream);
    hipMemsetAsync(accum, 0, (size_t)NN * HDIM * 4, stream);

    prep_x<<<(NN * CIN / 8 + 255) / 256, 256, 0, stream>>>(x, xb);
    prep_w<<<(416 * 256 + 255) / 256, 256, 0, stream>>>(Wq, Wk, Wv, Ws, WT);

    dim3 gGemm((NN + 127) / 128, 416 / 32);
    mfma_gemm<<<gGemm, 256, 0, stream>>>(xb, WT, bq, bk, bv, bs, qb, kb, vb, skip);

    const int tLog = EE * HEADS;
    edge_logits<<<(tLog + 255) / 256, 256, 0, stream>>>(qb, kb, ei, ew, ssum);
    edge_alpha<<<(tLog + 255) / 256, 256, 0, stream>>>(ei, ew, ssum);

    const int tAcc = EE * HDIM;
    edge_accum<<<(tAcc + 255) / 256, 256, 0, stream>>>(vb, ei, ew, accum);

    const int tFin = NN * HDIM;
    finalize<<<(tFin + 255) / 256, 256, 0, stream>>>(accum, skip, out);
}